// Round 7
// baseline (198.533 us; speedup 1.0000x reference)
//
#include <hip/hip_runtime.h>
#include <hip/hip_bf16.h>
#include <stdint.h>

#define NP 30000
#define BBINS 80
#define INCH 16
#define OUTCH 32
#define KDIM 1280       // BBINS*INCH
#define NDIM 512        // OUTCH*TBINS
#define KSTEPS 40       // KDIM/32
#define NROWS (NP * BBINS)   // 2,400,000
#define MTILES 118           // ceil(30000/256)

typedef __bf16 bf16x8 __attribute__((ext_vector_type(8)));
typedef __bf16 bf16x4 __attribute__((ext_vector_type(4)));
typedef float f32x4 __attribute__((ext_vector_type(4)));

__device__ __forceinline__ void async_ld16(const void* g, void* l) {
    __builtin_amdgcn_global_load_lds(
        (const __attribute__((address_space(1))) unsigned int*)g,
        (__attribute__((address_space(3))) unsigned int*)l,
        16, 0, 0);
}

// ---------------------------------------------------------------------------
// Prep: PW[kc][n][slot][e] bf16; slot s holds data k-chunk s ^ ((n>>1)&3)
// (conflict-free ds_read_b128 B fragments after verbatim LDS staging).
// lw[k][n] = W[(b+5t)%80][c][o], k=b*16+c, n=o*16+t.
// ---------------------------------------------------------------------------
__global__ void prep_weights(const float* __restrict__ w, __bf16* __restrict__ pw) {
    int gid = blockIdx.x * 256 + threadIdx.x;           // 655360 total
    int e  = gid & 7;
    int qs = (gid >> 3) & 3;                             // slot
    int n  = (gid >> 5) & 511;
    int kc = gid >> 14;                                  // 0..39
    int kp = kc * 32 + ((qs ^ ((n >> 1) & 3)) << 3) + e; // data k index
    int b = kp >> 4, c = kp & 15;
    int o = n >> 4,  t = n & 15;
    int bid = (b + 5 * t) % BBINS;
    pw[gid] = (__bf16)w[(bid * INCH + c) * OUTCH + o];
}

// ---------------------------------------------------------------------------
// Gather: 4 lanes per (patch,bin) row, natural h layout h[r*32 + q*8 ..]
// (the GEMM swizzles during its ds_write now).
// At the per-CU line-rate floor (~28k x-lines/CU) — structurally bound.
// ---------------------------------------------------------------------------
__global__ __launch_bounds__(256) void gather_h(
    const float* __restrict__ x,
    const int*   __restrict__ cidx,
    const float* __restrict__ cval,
    __bf16* __restrict__ h) {
    __shared__ int   ci[192];
    __shared__ float cv[192];
    const int t  = threadIdx.x;
    const int r0 = blockIdx.x * 64;

    if (t < 48)
        ((int4*)ci)[t] = ((const int4*)(cidx + (size_t)r0 * 3))[t];
    else if (t >= 64 && t < 112)
        ((float4*)cv)[t - 64] = ((const float4*)(cval + (size_t)r0 * 3))[t - 64];
    __syncthreads();

    const int rl = t >> 2;               // 0..63
    const int q  = t & 3;                // channel quad
    const int i0 = ci[rl * 3 + 0], i1 = ci[rl * 3 + 1], i2 = ci[rl * 3 + 2];
    const float v0 = cv[rl * 3 + 0], v1 = cv[rl * 3 + 1], v2 = cv[rl * 3 + 2];

    const float4 a = *(const float4*)(x + (size_t)i0 * 16 + q * 4);
    const float4 b = *(const float4*)(x + (size_t)i1 * 16 + q * 4);
    const float4 c = *(const float4*)(x + (size_t)i2 * 16 + q * 4);
    bf16x4 hv;
    hv[0] = (__bf16)(v0 * a.x + v1 * b.x + v2 * c.x);
    hv[1] = (__bf16)(v0 * a.y + v1 * b.y + v2 * c.y);
    hv[2] = (__bf16)(v0 * a.z + v1 * b.z + v2 * c.z);
    hv[3] = (__bf16)(v0 * a.w + v1 * b.w + v2 * c.w);

    const int r = r0 + rl;
    // natural layout: row r, channels [q*4, q*4+4)  (R6 bug: q*8 was missing)
    *(bf16x4*)((char*)h + (size_t)r * 32 + q * 8) = hv;
}

// ---------------------------------------------------------------------------
// GEMM + max-over-t.  512 threads (8 waves, 4x2), tile 256 rows x 256 cols
// (M=256 halves B restaging lines vs M=128 — B-lines were 2x A-lines).
// Per kstep/block: A 256 unique lines (reg->ds_write), B 256 (global_load_lds).
// Order: [barrier] -> A reg-loads (oldest) -> B asyncs -> ds_read+MFMA ->
// vmcnt(2) waits only A -> ds_write(next buf) -> [barrier] (B had full kstep).
// A ds_write applies the chunk-XOR swizzle; B pre-swizzled by prep.
// ---------------------------------------------------------------------------
__global__ __launch_bounds__(512, 2) void gemm_max(
    const __bf16* __restrict__ h,
    const __bf16* __restrict__ pw,
    float* __restrict__ out) {

    __shared__ __align__(16) char Abuf[2][16384];   // 256 rows x 64 B
    __shared__ __align__(16) char Bbuf[2][16384];   // 256 cols x 64 B

    const int bid = blockIdx.x;
    const int m    = (bid >> 4) * 8 + (bid & 7);     // 0..119
    const int ncol = (bid >> 3) & 1;                 // 0/1 (pairs g,g+8 same XCD)
    if (m >= MTILES) return;                         // 4 dead pad blocks
    const int mbase = m * 256;

    const int tid  = threadIdx.x;
    const int lane = tid & 63;
    const int wave = tid >> 6;
    const int wm = wave >> 1;            // 0..3
    const int wc = wave & 1;             // 0..1

    int a_off[4], b_off[8];
    {
        const int ml = lane & 15, q = lane >> 4;
        const int swz = (q ^ ((ml >> 1) & 3)) << 4;
#pragma unroll
        for (int i = 0; i < 4; ++i)
            a_off[i] = (wm * 64 + i * 16 + ml) * 64 + swz;
#pragma unroll
        for (int j = 0; j < 8; ++j)
            b_off[j] = (wc * 128 + j * 16 + ml) * 64 + swz;
    }

    f32x4 acc[4][8];
#pragma unroll
    for (int i = 0; i < 4; ++i)
#pragma unroll
        for (int j = 0; j < 8; ++j)
            acc[i][j] = (f32x4){0.f, 0.f, 0.f, 0.f};

    // A staging role: lane-quad per row, 2 passes (rows t>>2 and t>>2+128).
    const int aq = tid & 3;                          // chunk quad
    int rL0 = (tid >> 2);                            // local row, pass 0
    int rL1 = rL0 + 128;                             // local row, pass 1
    int rG0 = mbase + rL0, rG1 = mbase + rL1;
    if (rG0 > NP - 1) rG0 = NP - 1;
    if (rG1 > NP - 1) rG1 = NP - 1;
    const char* aSrc0 = (const char*)h + (size_t)rG0 * 2560 + aq * 16;
    const char* aSrc1 = (const char*)h + (size_t)rG1 * 2560 + aq * 16;
    const int aDst0 = rL0 * 64 + ((aq ^ ((rL0 >> 1) & 3)) << 4);
    const int aDst1 = rL1 * 64 + ((aq ^ ((rL1 >> 1) & 3)) << 4);

    const char* bSrc = (const char*)pw + ncol * 16384 + tid * 16;
    const int ldsOff = tid * 16;

    // ---- prologue: stage kstep 0 into buf 0
    {
        bf16x8 a0 = *(const bf16x8*)(aSrc0);
        bf16x8 a1 = *(const bf16x8*)(aSrc1);
        async_ld16(bSrc, Bbuf[0] + ldsOff);
        async_ld16(bSrc + 8192, Bbuf[0] + 8192 + ldsOff);
        *(bf16x8*)(Abuf[0] + aDst0) = a0;
        *(bf16x8*)(Abuf[0] + aDst1) = a1;
    }
    __syncthreads();

    for (int kc = 0; kc < KSTEPS; ++kc) {
        const int cur = kc & 1, nxt = cur ^ 1;
        bf16x8 a0, a1;
        const bool more = (kc + 1 < KSTEPS);
        if (more) {
            // A loads FIRST (become the oldest outstanding VMEM -> the
            // pre-ds_write waitcnt is vmcnt(2), leaving B asyncs in flight)
            a0 = *(const bf16x8*)(aSrc0 + (kc + 1) * 64);
            a1 = *(const bf16x8*)(aSrc1 + (kc + 1) * 64);
            const char* bs = bSrc + (size_t)(kc + 1) * 32768;
            async_ld16(bs, Bbuf[nxt] + ldsOff);
            async_ld16(bs + 8192, Bbuf[nxt] + 8192 + ldsOff);
        }

        bf16x8 af[4], bfr[8];
#pragma unroll
        for (int i = 0; i < 4; ++i)
            af[i] = *(const bf16x8*)(Abuf[cur] + a_off[i]);
#pragma unroll
        for (int j = 0; j < 8; ++j)
            bfr[j] = *(const bf16x8*)(Bbuf[cur] + b_off[j]);
#pragma unroll
        for (int i = 0; i < 4; ++i)
#pragma unroll
            for (int j = 0; j < 8; ++j)
                acc[i][j] = __builtin_amdgcn_mfma_f32_16x16x32_bf16(
                    af[i], bfr[j], acc[i][j], 0, 0, 0);

        if (more) {
            *(bf16x8*)(Abuf[nxt] + aDst0) = a0;
            *(bf16x8*)(Abuf[nxt] + aDst1) = a1;
        }
        __syncthreads();
    }

    // ---- epilogue: max over t (t = col = lane&15), store o = n>>4
    const int rgrp = lane >> 4;
    const int tl   = lane & 15;
#pragma unroll
    for (int i = 0; i < 4; ++i) {
#pragma unroll
        for (int j = 0; j < 8; ++j) {
            float v0 = acc[i][j][0], v1 = acc[i][j][1];
            float v2 = acc[i][j][2], v3 = acc[i][j][3];
#pragma unroll
            for (int off = 1; off < 16; off <<= 1) {
                v0 = fmaxf(v0, __shfl_xor(v0, off));
                v1 = fmaxf(v1, __shfl_xor(v1, off));
                v2 = fmaxf(v2, __shfl_xor(v2, off));
                v3 = fmaxf(v3, __shfl_xor(v3, off));
            }
            if (tl == 0) {
                const int o  = ncol * 16 + wc * 8 + j;
                const int pr = mbase + wm * 64 + i * 16 + rgrp * 4;
                if (pr + 0 < NP) out[(pr + 0) * 32 + o] = v0;
                if (pr + 1 < NP) out[(pr + 1) * 32 + o] = v1;
                if (pr + 2 < NP) out[(pr + 2) * 32 + o] = v2;
                if (pr + 3 < NP) out[(pr + 3) * 32 + o] = v3;
            }
        }
    }
}

extern "C" void kernel_launch(void* const* d_in, const int* in_sizes, int n_in,
                              void* d_out, int out_size, void* d_ws, size_t ws_size,
                              hipStream_t stream) {
    const float* x    = (const float*)d_in[0];
    const int*   cidx = (const int*)d_in[1];
    const float* cval = (const float*)d_in[2];
    const float* w    = (const float*)d_in[3];
    float* out = (float*)d_out;

    __bf16* pw = (__bf16*)d_ws;                               // 1.31 MB
    __bf16* h  = (__bf16*)((char*)d_ws + (2 << 20));          // 76.8 MB @ +2MB

    hipLaunchKernelGGL(prep_weights, dim3(2560), dim3(256), 0, stream, w, pw);
    hipLaunchKernelGGL(gather_h, dim3(NROWS / 64), dim3(256), 0, stream,
                       x, cidx, cval, h);
    hipLaunchKernelGGL(gemm_max, dim3(240), dim3(512), 0, stream,
                       h, (const __bf16*)pw, out);
}